// Round 4
// baseline (2909.830 us; speedup 1.0000x reference)
//
#include <hip/hip_runtime.h>
#include <limits.h>
#include <math.h>

// CalcImpute: per-row top-16-smallest (stable: lexicographic (value,index))
// over 50000 donors, then masked mean of gathered donor values.
// Round 4: DRAM-locality restructure. 16 waves (1024 threads) cooperate on
// ONE row so the block's active read front is a contiguous 32-64 KB region
// and a 200 KB row is fully consumed in ~4 us (vs the whole kernel duration
// when one wave owned a row). Per-wave replicated top-16 + exact threshold
// gate as before; new LDS merge of 16 per-wave lists at the end.

#define K          16
#define NDON       50000
#define NF4        12500             // float4 per row
#define WPB        16                // waves per block
#define TPB        (WPB * 64)        // 1024 threads
#define BSTEP_F4   (WPB * 128)       // 2048 f4 per block-step (2 f4/lane)
#define FULL_STEPS 6                 // 6*2048 = 12288 f4
#define TAIL_F4    12288             // remaining 212 f4 handled by waves 0,1

__device__ __forceinline__ bool lexless(float v1, int i1, float v2, int i2) {
    return (v1 < v2) || ((v1 == v2) && (i1 < i2));
}

__device__ __forceinline__ float nanfix(float v) { return (v != v) ? 1e10f : v; }

// Insert candidate (cv,ci) into the sorted (ascending lex) replicated list.
// (cv,ci) are wave-uniform; all control flow here is wave-uniform.
__device__ __forceinline__ void insert16(float (&vals)[K], int (&idxs)[K],
                                         float cv, int ci) {
    if (!lexless(cv, ci, vals[K - 1], idxs[K - 1])) return;
    bool prev = true;  // cand < vals[15] (guard above)
#pragma unroll
    for (int j = K - 1; j >= 1; --j) {
        const bool up = lexless(cv, ci, vals[j - 1], idxs[j - 1]);
        const float nv = up ? vals[j - 1] : (prev ? cv : vals[j]);
        const int   ni = up ? idxs[j - 1] : (prev ? ci : idxs[j]);
        vals[j] = nv; idxs[j] = ni;
        prev = up;
    }
    if (prev) { vals[0] = cv; idxs[0] = ci; }
}

// compare-exchange for 4-sorts
#define CE(va, ia, vb, ib)                                         \
    {                                                              \
        const bool sw_ = lexless(vb, ib, va, ia);                  \
        const float tv_ = va; const int ti_ = ia;                  \
        va = sw_ ? vb : va; ia = sw_ ? ib : ia;                    \
        vb = sw_ ? tv_ : vb; ib = sw_ ? ti_ : ib;                  \
    }

__global__ void __launch_bounds__(TPB, 8)
calc_impute_topk(const float* __restrict__ dist,
                 const float* __restrict__ fitX,
                 const int*   __restrict__ mask,
                 float* __restrict__ out,
                 int nrows)
{
    const int row  = blockIdx.x;                 // one row per block
    const int lane = threadIdx.x & 63;
    const int w    = threadIdx.x >> 6;           // wave id 0..15
    if (row >= nrows) return;

    const float4* __restrict__ r4 =
        reinterpret_cast<const float4*>(dist + (size_t)row * NDON);
    const int wbase = w * 128 + lane;            // f4 index of group A, step 0

    // Issue the wave's first two groups + step-1 prefetch up front.
    float4 a  = r4[wbase];
    float4 b  = r4[wbase + 64];
    float4 c0 = r4[BSTEP_F4 + wbase];
    float4 c1 = r4[BSTEP_F4 + wbase + 64];

    // ---- Per-wave prologue: exact top-16 of the wave's first 256 elems ----
    float l0 = nanfix(a.x), l1 = nanfix(a.y), l2 = nanfix(a.z), l3 = nanfix(a.w);
    int   j0 = wbase * 4, j1 = j0 + 1, j2 = j0 + 2, j3 = j0 + 3;
    CE(l0, j0, l1, j1); CE(l2, j2, l3, j3);
    CE(l0, j0, l2, j2); CE(l1, j1, l3, j3);
    CE(l1, j1, l2, j2);

    float vals[K];
    int   idxs[K];
#pragma unroll
    for (int r = 0; r < K; ++r) {
        float mv = l0; int mi = j0;
#pragma unroll
        for (int m = 32; m >= 1; m >>= 1) {
            const float ov = __shfl_xor(mv, m, 64);
            const int   oi = __shfl_xor(mi, m, 64);
            if (lexless(ov, oi, mv, mi)) { mv = ov; mi = oi; }
        }
        vals[r] = mv; idxs[r] = mi;          // wave-uniform
        if (l0 == mv && j0 == mi) {          // unique winner pops its head
            l0 = l1; j0 = j1; l1 = l2; j1 = j2; l2 = l3; j2 = j3;
            l3 = INFINITY; j3 = INT_MAX;
        }
    }
    float Tv = vals[K - 1];                  // exact running 16th (this wave)

    // Candidates passing (x <= Tv) are finite (NaN fails the compare and its
    // reference value 1e10 > Tv for this data), so no nanfix in the hot path.
#define PROC(ve, ie)                                                   \
    {                                                                  \
        unsigned long long bb_ = __ballot((ve) <= Tv);                 \
        while (bb_) {                                                  \
            const int src_ = __builtin_ctzll(bb_); bb_ &= bb_ - 1;     \
            const float cv_ = __shfl((ve), src_, 64);                  \
            const int   ci_ = __shfl((ie), src_, 64);                  \
            insert16(vals, idxs, cv_, ci_);                            \
        }                                                              \
    }

    // ---- Group B of step 0 ----
    {
        const int eb = (wbase + 64) * 4;
        PROC(b.x, eb + 0); PROC(b.y, eb + 1);
        PROC(b.z, eb + 2); PROC(b.w, eb + 3);
        Tv = vals[K - 1];
    }

    // ---- Steps 1..5: 2 f4/lane, prefetch depth 1 ----
#pragma unroll 1
    for (int s = 1; s < FULL_STEPS; ++s) {
        float4 n0, n1;
        const bool more = (s + 1 < FULL_STEPS);
        if (more) {
            n0 = r4[(s + 1) * BSTEP_F4 + wbase];
            n1 = r4[(s + 1) * BSTEP_F4 + wbase + 64];
        }
        const float m0 = fminf(fminf(c0.x, c0.y), fminf(c0.z, c0.w));
        const float m1 = fminf(fminf(c1.x, c1.y), fminf(c1.z, c1.w));
        if (__any(fminf(m0, m1) <= Tv)) {
            const int e0 = (s * BSTEP_F4 + wbase) * 4;
            PROC(c0.x, e0 + 0);   PROC(c0.y, e0 + 1);
            PROC(c0.z, e0 + 2);   PROC(c0.w, e0 + 3);
            PROC(c1.x, e0 + 256); PROC(c1.y, e0 + 257);
            PROC(c1.z, e0 + 258); PROC(c1.w, e0 + 259);
            Tv = vals[K - 1];
        }
        c0 = n0; c1 = n1;
    }

    // ---- Tail: f4 [12288, 12500) -> waves 0 and 1 only ----
    if (w < 2) {
        const int fa = TAIL_F4 + wbase;          // w0: 12288+l, w1: 12416+l
        float4 e = r4[fa];                        // always < 12500
        const int ea = fa * 4;
        PROC(e.x, ea + 0); PROC(e.y, ea + 1);
        PROC(e.z, ea + 2); PROC(e.w, ea + 3);
        Tv = vals[K - 1];
        const int fb = fa + 64;                   // w1 group B: partial
        float4 f;
        if (fb < NF4) {
            f = r4[fb];
        } else {
            f.x = f.y = f.z = f.w = INFINITY;
        }
        const int eb = fb * 4;
        PROC(f.x, eb + 0); PROC(f.y, eb + 1);
        PROC(f.z, eb + 2); PROC(f.w, eb + 3);
    }
#undef PROC

    // ---- Export per-wave top-16 to LDS ----
    __shared__ float lv[WPB * K];
    __shared__ int   li[WPB * K];
    float ev = INFINITY; int ei = INT_MAX;
#pragma unroll
    for (int j = 0; j < K; ++j) {
        if (lane == j) { ev = vals[j]; ei = idxs[j]; }
    }
    if (lane < K) { lv[w * K + lane] = ev; li[w * K + lane] = ei; }
    __syncthreads();

    // ---- Wave 0 merges the 256 candidates and writes the output ----
    if (threadIdx.x < 64) {
        float4 mv4 = reinterpret_cast<const float4*>(lv)[lane];
        int4   mi4 = reinterpret_cast<const int4*>(li)[lane];
        float g0 = mv4.x, g1 = mv4.y, g2 = mv4.z, g3 = mv4.w;
        int   h0 = mi4.x, h1 = mi4.y, h2 = mi4.z, h3 = mi4.w;
        CE(g0, h0, g1, h1); CE(g2, h2, g3, h3);
        CE(g0, h0, g2, h2); CE(g1, h1, g3, h3);
        CE(g1, h1, g2, h2);

        float s_w = 0.0f, s_wx = 0.0f;
#pragma unroll
        for (int r = 0; r < K; ++r) {
            float mv = g0; int mi = h0;
#pragma unroll
            for (int m = 32; m >= 1; m >>= 1) {
                const float ov = __shfl_xor(mv, m, 64);
                const int   oi = __shfl_xor(mi, m, 64);
                if (lexless(ov, oi, mv, mi)) { mv = ov; mi = oi; }
            }
            if (g0 == mv && h0 == mi) {      // unique winner pops its head
                g0 = g1; h0 = h1; g1 = g2; h1 = h2; g2 = g3; h2 = h3;
                g3 = INFINITY; h3 = INT_MAX;
            }
            const float wgt = 1.0f - (float)mask[mi];   // uniform -> broadcast
            s_w  += wgt;
            s_wx += wgt * fitX[mi];
        }
        if (lane == 0) {
            out[row] = s_wx / ((s_w == 0.0f) ? 1.0f : s_w);
        }
    }
}

extern "C" void kernel_launch(void* const* d_in, const int* in_sizes, int n_in,
                              void* d_out, int out_size, void* d_ws, size_t ws_size,
                              hipStream_t stream) {
    const float* dist = (const float*)d_in[0];
    // d_in[1] is n_neighbors (==16, fixed; K hardcoded)
    const float* fitX = (const float*)d_in[2];
    const int*   mask = (const int*)d_in[3];
    float* out = (float*)d_out;

    const int nrows = out_size;                 // 8192
    calc_impute_topk<<<nrows, TPB, 0, stream>>>(dist, fitX, mask, out, nrows);
}

// Round 5
// 849.276 us; speedup vs baseline: 3.4262x; 3.4262x over previous
//
#include <hip/hip_runtime.h>
#include <limits.h>
#include <math.h>

// CalcImpute: per-row top-16-smallest (stable: lexicographic (value,index))
// over 50000 donors, then masked mean of gathered donor values.
// Round 5: DRAM/TLB-locality restructure WITHOUT register spills.
// One row per 256-thread block; each of the 4 waves owns a CONTIGUOUS
// quarter-row (50 KB), so co-resident read fronts are spaced 50 KB (vs
// 200 KB in round 3) and the active page set shrinks ~8x. Per-wave
// replicated top-16 + exact threshold gate (round 2/3 machinery, VGPR~90,
// no launch-bounds pressure). 4-list LDS merge on wave 0.

#define K     16
#define NDON  50000
#define NF4   12500             // float4 per row
#define QF4   3125              // float4 per wave (quarter row)
#define WPB   4                 // waves per block
#define TPB   (WPB * 64)        // 256 threads
// per-wave coverage: prologue 64 f4 + 11 iters x 256 f4 + tail 245 f4 = 3125

__device__ __forceinline__ bool lexless(float v1, int i1, float v2, int i2) {
    return (v1 < v2) || ((v1 == v2) && (i1 < i2));
}

__device__ __forceinline__ float nanfix(float v) { return (v != v) ? 1e10f : v; }

// Insert candidate (cv,ci) into the sorted (ascending lex) replicated list.
// (cv,ci) are wave-uniform; all control flow here is wave-uniform.
__device__ __forceinline__ void insert16(float (&vals)[K], int (&idxs)[K],
                                         float cv, int ci) {
    if (!lexless(cv, ci, vals[K - 1], idxs[K - 1])) return;
    bool prev = true;  // cand < vals[15] (guard above)
#pragma unroll
    for (int j = K - 1; j >= 1; --j) {
        const bool up = lexless(cv, ci, vals[j - 1], idxs[j - 1]);
        const float nv = up ? vals[j - 1] : (prev ? cv : vals[j]);
        const int   ni = up ? idxs[j - 1] : (prev ? ci : idxs[j]);
        vals[j] = nv; idxs[j] = ni;
        prev = up;
    }
    if (prev) { vals[0] = cv; idxs[0] = ci; }
}

// compare-exchange for 4-sorts
#define CE(va, ia, vb, ib)                                         \
    {                                                              \
        const bool sw_ = lexless(vb, ib, va, ia);                  \
        const float tv_ = va; const int ti_ = ia;                  \
        va = sw_ ? vb : va; ia = sw_ ? ib : ia;                    \
        vb = sw_ ? tv_ : vb; ib = sw_ ? ti_ : ib;                  \
    }

__global__ void __launch_bounds__(TPB, 4)
calc_impute_topk(const float* __restrict__ dist,
                 const float* __restrict__ fitX,
                 const int*   __restrict__ mask,
                 float* __restrict__ out,
                 int nrows)
{
    const int row  = blockIdx.x;                 // one row per block
    const int lane = threadIdx.x & 63;
    const int w    = threadIdx.x >> 6;           // wave id 0..3
    if (row >= nrows) return;                    // grid == nrows; never taken

    const float4* __restrict__ r4 =
        reinterpret_cast<const float4*>(dist + (size_t)row * NDON);
    const int qbase = w * QF4;                   // this wave's quarter start

    // Issue prologue group + iter-0 groups up front.
    float4 a = r4[qbase + lane];
    const float4* p0 = r4 + qbase + 64 + lane;
    float4 c0 = p0[0], c1 = p0[64], c2 = p0[128], c3 = p0[192];

    // ---- Prologue: exact top-16 of the quarter's first 256 elements ----
    float l0 = nanfix(a.x), l1 = nanfix(a.y), l2 = nanfix(a.z), l3 = nanfix(a.w);
    int   j0 = (qbase + lane) * 4, j1 = j0 + 1, j2 = j0 + 2, j3 = j0 + 3;
    CE(l0, j0, l1, j1); CE(l2, j2, l3, j3);
    CE(l0, j0, l2, j2); CE(l1, j1, l3, j3);
    CE(l1, j1, l2, j2);

    float vals[K];
    int   idxs[K];
#pragma unroll
    for (int r = 0; r < K; ++r) {
        float mv = l0; int mi = j0;
#pragma unroll
        for (int m = 32; m >= 1; m >>= 1) {
            const float ov = __shfl_xor(mv, m, 64);
            const int   oi = __shfl_xor(mi, m, 64);
            if (lexless(ov, oi, mv, mi)) { mv = ov; mi = oi; }
        }
        vals[r] = mv; idxs[r] = mi;          // wave-uniform
        if (l0 == mv && j0 == mi) {          // unique winner pops its head
            l0 = l1; j0 = j1; l1 = l2; j1 = j2; l2 = l3; j2 = j3;
            l3 = INFINITY; j3 = INT_MAX;
        }
    }
    float Tv = vals[K - 1];                  // exact running 16th (this wave)

    // Candidates passing (x <= Tv) are finite (NaN fails the compare and its
    // reference value 1e10 > Tv for this data), so no nanfix in the hot path.
#define PROC(ve, ie)                                                   \
    {                                                                  \
        unsigned long long bb_ = __ballot((ve) <= Tv);                 \
        while (bb_) {                                                  \
            const int src_ = __builtin_ctzll(bb_); bb_ &= bb_ - 1;     \
            const float cv_ = __shfl((ve), src_, 64);                  \
            const int   ci_ = __shfl((ie), src_, 64);                  \
            insert16(vals, idxs, cv_, ci_);                            \
        }                                                              \
    }

    // ---- Main: 11 iters x 4 f4/lane (256 f4/wave-iter), prefetch depth 1 ----
#pragma unroll 1
    for (int s = 0; s < 11; ++s) {
        float4 n0, n1, n2, n3;
        const bool more = (s + 1 < 11);
        if (more) {
            const float4* pn = r4 + qbase + 64 + (s + 1) * 256 + lane;
            n0 = pn[0]; n1 = pn[64]; n2 = pn[128]; n3 = pn[192];
        }
        const float m0 = fminf(fminf(c0.x, c0.y), fminf(c0.z, c0.w));
        const float m1 = fminf(fminf(c1.x, c1.y), fminf(c1.z, c1.w));
        const float m2 = fminf(fminf(c2.x, c2.y), fminf(c2.z, c2.w));
        const float m3 = fminf(fminf(c3.x, c3.y), fminf(c3.z, c3.w));
        if (__any(fminf(fminf(m0, m1), fminf(m2, m3)) <= Tv)) {
            const int e0 = (qbase + 64 + s * 256 + lane) * 4;
            PROC(c0.x, e0 + 0);   PROC(c0.y, e0 + 1);
            PROC(c0.z, e0 + 2);   PROC(c0.w, e0 + 3);
            PROC(c1.x, e0 + 256); PROC(c1.y, e0 + 257);
            PROC(c1.z, e0 + 258); PROC(c1.w, e0 + 259);
            PROC(c2.x, e0 + 512); PROC(c2.y, e0 + 513);
            PROC(c2.z, e0 + 514); PROC(c2.w, e0 + 515);
            PROC(c3.x, e0 + 768); PROC(c3.y, e0 + 769);
            PROC(c3.z, e0 + 770); PROC(c3.w, e0 + 771);
            Tv = vals[K - 1];
        }
        c0 = n0; c1 = n1; c2 = n2; c3 = n3;
    }

    // ---- Tail: f4 [qbase+2880, qbase+3125) = 3 full groups + 53 masked ----
    {
        const int tb = qbase + 2880 + lane;
        float4 t0 = r4[tb], t1 = r4[tb + 64], t2 = r4[tb + 128];
        float4 t3;
        if (lane < 53) {
            t3 = r4[tb + 192];
        } else {
            t3.x = t3.y = t3.z = t3.w = INFINITY;
        }
        const int e0 = tb * 4;
        PROC(t0.x, e0 + 0);   PROC(t0.y, e0 + 1);
        PROC(t0.z, e0 + 2);   PROC(t0.w, e0 + 3);
        PROC(t1.x, e0 + 256); PROC(t1.y, e0 + 257);
        PROC(t1.z, e0 + 258); PROC(t1.w, e0 + 259);
        PROC(t2.x, e0 + 512); PROC(t2.y, e0 + 513);
        PROC(t2.z, e0 + 514); PROC(t2.w, e0 + 515);
        PROC(t3.x, e0 + 768); PROC(t3.y, e0 + 769);
        PROC(t3.z, e0 + 770); PROC(t3.w, e0 + 771);
    }
#undef PROC

    // ---- Export per-wave top-16 to LDS ----
    __shared__ float lv[WPB * K];
    __shared__ int   li[WPB * K];
    float ev = INFINITY; int ei = INT_MAX;
#pragma unroll
    for (int j = 0; j < K; ++j) {
        if (lane == j) { ev = vals[j]; ei = idxs[j]; }
    }
    if (lane < K) { lv[w * K + lane] = ev; li[w * K + lane] = ei; }
    __syncthreads();

    // ---- Wave 0 merges the 64 candidates and writes the output ----
    if (threadIdx.x < 64) {
        float g = lv[lane];                  // one candidate per lane
        int   h = li[lane];
        float s_w = 0.0f, s_wx = 0.0f;
#pragma unroll
        for (int r = 0; r < K; ++r) {
            float mv = g; int mi = h;
#pragma unroll
            for (int m = 32; m >= 1; m >>= 1) {
                const float ov = __shfl_xor(mv, m, 64);
                const int   oi = __shfl_xor(mi, m, 64);
                if (lexless(ov, oi, mv, mi)) { mv = ov; mi = oi; }
            }
            if (g == mv && h == mi) {        // unique winner retires
                g = INFINITY; h = INT_MAX;
            }
            const float wgt = 1.0f - (float)mask[mi];   // uniform -> broadcast
            s_w  += wgt;
            s_wx += wgt * fitX[mi];
        }
        if (lane == 0) {
            out[row] = s_wx / ((s_w == 0.0f) ? 1.0f : s_w);
        }
    }
}

extern "C" void kernel_launch(void* const* d_in, const int* in_sizes, int n_in,
                              void* d_out, int out_size, void* d_ws, size_t ws_size,
                              hipStream_t stream) {
    const float* dist = (const float*)d_in[0];
    // d_in[1] is n_neighbors (==16, fixed; K hardcoded)
    const float* fitX = (const float*)d_in[2];
    const int*   mask = (const int*)d_in[3];
    float* out = (float*)d_out;

    const int nrows = out_size;                 // 8192
    calc_impute_topk<<<nrows, TPB, 0, stream>>>(dist, fitX, mask, out, nrows);
}

// Round 6
// 351.296 us; speedup vs baseline: 8.2831x; 2.4176x over previous
//
#include <hip/hip_runtime.h>
#include <limits.h>
#include <math.h>

// CalcImpute: per-row top-16-smallest (stable lex (value,index)) over 50000
// donors, then masked mean of gathered donor values.
// Round 6: scan+compact. K1 streams the 1.64 GB dist matrix with a CHIP-WIDE
// LINEAR front (memcpy-shaped grid-stride; 2048 fully-resident blocks reading
// consecutive 16 KB chunks) and appends rare candidates (val < TAU) to
// per-row buckets as packed u64 keys. K2 does exact top-16 per row from the
// bucket (wave-wide u64-min pops); rows with too-few/too-many candidates take
// an exact full-row rescan fallback. K0 zeroes counters (replay-safe).

#define NROWS 8192
#define NDON  50000
#define NF4   12500
#define K     16
#define TAU   1.0e-3f        // E[hits/row]=50; P(<16)~6e-9, P(>128)~1e-20
#define CAP   128
#define SUPER 100000         // super-chunks of 1024 f4 (16 KB); *1024 = all f4

typedef unsigned long long u64;

__device__ __forceinline__ bool lexless(float v1, int i1, float v2, int i2) {
    return (v1 < v2) || ((v1 == v2) && (i1 < i2));
}
__device__ __forceinline__ float nanfix(float v) { return (v != v) ? 1e10f : v; }

// ---------------- K0: zero per-row counters ----------------
__global__ void k_zero(int* __restrict__ cnt) {
    const int i = blockIdx.x * blockDim.x + threadIdx.x;
    if (i < NROWS) cnt[i] = 0;
}

// ---------------- K1: linear-front scan + compact ----------------
__global__ void __launch_bounds__(256, 8)
k_scan(const float4* __restrict__ d4, u64* __restrict__ buck,
       int* __restrict__ cnt) {
    const int t = threadIdx.x;

#define EMIT(vf, ee)                                                        \
    if ((vf) < TAU) {                                                       \
        const int e_ = (ee);                                                \
        const int row_ = e_ / NDON;                                         \
        const int col_ = e_ - row_ * NDON;                                  \
        const int pos_ = atomicAdd(&cnt[row_], 1);                          \
        if (pos_ < CAP)                                                     \
            buck[(size_t)row_ * CAP + pos_] =                               \
                ((u64)__float_as_uint(vf) << 32) | (unsigned)col_;          \
    }
#define EMIT4(q, fi)                                                        \
    {                                                                       \
        const int e0_ = (fi) * 4;                                           \
        EMIT(q.x, e0_); EMIT(q.y, e0_ + 1);                                 \
        EMIT(q.z, e0_ + 2); EMIT(q.w, e0_ + 3);                             \
    }

    for (int sc = blockIdx.x; sc < SUPER; sc += gridDim.x) {
        const int F = sc * 1024 + t;          // f4 index; block reads 16 KB
        const float4 a = d4[F];
        const float4 b = d4[F + 256];
        const float4 c = d4[F + 512];
        const float4 d = d4[F + 768];
        const float ma = fminf(fminf(a.x, a.y), fminf(a.z, a.w));
        const float mb = fminf(fminf(b.x, b.y), fminf(b.z, b.w));
        const float mc = fminf(fminf(c.x, c.y), fminf(c.z, c.w));
        const float md = fminf(fminf(d.x, d.y), fminf(d.z, d.w));
        if (fminf(fminf(ma, mb), fminf(mc, md)) < TAU) {   // rare
            if (ma < TAU) EMIT4(a, F);
            if (mb < TAU) EMIT4(b, F + 256);
            if (mc < TAU) EMIT4(c, F + 512);
            if (md < TAU) EMIT4(d, F + 768);
        }
    }
#undef EMIT4
#undef EMIT
}

// ---------------- K2: per-row merge (+exact fallback) ----------------
__global__ void __launch_bounds__(64)
k_merge(const u64* __restrict__ buck, const int* __restrict__ cnt,
        const float* __restrict__ dist, const float* __restrict__ fitX,
        const int* __restrict__ mask, float* __restrict__ out, int nrows) {
    const int row = blockIdx.x;
    const int lane = threadIdx.x;             // one wave per row
    if (row >= nrows) return;

    const int n = cnt[row];
    float s_w = 0.0f, s_wx = 0.0f;

    if (n >= K && n <= CAP) {
        // Bucket holds ALL row elements < TAU (n <= CAP, none dropped) and
        // n >= 16 of them exist, so the global top-16 is inside the bucket.
        // Packed key (valbits<<32)|col: u64 order == lex (val,col) for the
        // non-negative finite values that pass (v < TAU).
        const u64* bp = buck + (size_t)row * CAP;
        u64 k0 = (lane < n)      ? bp[lane]      : ~0ull;
        u64 k1 = (lane + 64 < n) ? bp[lane + 64] : ~0ull;
        if (k1 < k0) { const u64 tt = k0; k0 = k1; k1 = tt; }
#pragma unroll
        for (int r = 0; r < K; ++r) {
            u64 mv = k0;                       // lane-local min (k0 <= k1)
#pragma unroll
            for (int m = 32; m >= 1; m >>= 1) {
                const u64 ov = __shfl_xor(mv, m, 64);
                if (ov < mv) mv = ov;
            }
            if (k0 == mv) { k0 = k1; k1 = ~0ull; }   // unique key pops
            const int col = (int)(unsigned)(mv & 0xffffffffu);
            const float w = 1.0f - (float)mask[col]; // uniform -> broadcast
            s_w  += w;
            s_wx += w * fitX[col];
        }
    } else {
        // Exact fallback: full-row rescan with replicated top-16 list.
        // (Essentially never taken on this data; correctness guarantee.)
        const float4* r4 = reinterpret_cast<const float4*>(dist + (size_t)row * NDON);
        float vals[K]; int idxs[K];
#pragma unroll
        for (int j = 0; j < K; ++j) { vals[j] = INFINITY; idxs[j] = INT_MAX; }
        float Tv = INFINITY;

#define PROC(ve, ie)                                                   \
    {                                                                  \
        unsigned long long bb_ = __ballot((ve) <= Tv);                 \
        while (bb_) {                                                  \
            const int src_ = __builtin_ctzll(bb_); bb_ &= bb_ - 1;     \
            const float cv_ = __shfl((ve), src_, 64);                  \
            const int   ci_ = __shfl((ie), src_, 64);                  \
            if (lexless(cv_, ci_, vals[K - 1], idxs[K - 1])) {         \
                vals[K - 1] = cv_; idxs[K - 1] = ci_;                  \
                for (int j_ = K - 1; j_ > 0; --j_) {                   \
                    if (lexless(vals[j_], idxs[j_],                    \
                                vals[j_ - 1], idxs[j_ - 1])) {         \
                        const float tv_ = vals[j_];                    \
                        const int ti_ = idxs[j_];                      \
                        vals[j_] = vals[j_ - 1]; idxs[j_] = idxs[j_ - 1]; \
                        vals[j_ - 1] = tv_; idxs[j_ - 1] = ti_;        \
                    } else break;                                      \
                }                                                      \
            }                                                          \
        }                                                              \
    }

        for (int it = 0; it < 196; ++it) {
            const int f4i = it * 64 + lane;
            float4 q;
            if (f4i < NF4) {
                q = r4[f4i];
            } else {
                q.x = q.y = q.z = q.w = INFINITY;
            }
            const float x0 = nanfix(q.x), x1 = nanfix(q.y),
                        x2 = nanfix(q.z), x3 = nanfix(q.w);
            const int e0 = f4i * 4;
            PROC(x0, e0 + 0); PROC(x1, e0 + 1);
            PROC(x2, e0 + 2); PROC(x3, e0 + 3);
            Tv = vals[K - 1];
        }
#undef PROC
#pragma unroll
        for (int r = 0; r < K; ++r) {
            const int col = idxs[r];
            const float w = 1.0f - (float)mask[col];
            s_w  += w;
            s_wx += w * fitX[col];
        }
    }

    if (lane == 0) {
        out[row] = s_wx / ((s_w == 0.0f) ? 1.0f : s_w);
    }
}

// ---------------- monolithic fallback (round-3 kernel, 387 us) ----------------
// Used only if ws_size is too small for the bucket scheme.
__device__ __forceinline__ void insert16m(float (&vals)[K], int (&idxs)[K],
                                          float cv, int ci) {
    if (!lexless(cv, ci, vals[K - 1], idxs[K - 1])) return;
    bool prev = true;
#pragma unroll
    for (int j = K - 1; j >= 1; --j) {
        const bool up = lexless(cv, ci, vals[j - 1], idxs[j - 1]);
        const float nv = up ? vals[j - 1] : (prev ? cv : vals[j]);
        const int   ni = up ? idxs[j - 1] : (prev ? ci : idxs[j]);
        vals[j] = nv; idxs[j] = ni;
        prev = up;
    }
    if (prev) { vals[0] = cv; idxs[0] = ci; }
}

#define CE(va, ia, vb, ib)                                         \
    {                                                              \
        const bool sw_ = lexless(vb, ib, va, ia);                  \
        const float tv_ = va; const int ti_ = ia;                  \
        va = sw_ ? vb : va; ia = sw_ ? ib : ia;                    \
        vb = sw_ ? tv_ : vb; ib = sw_ ? ti_ : ib;                  \
    }

__global__ void __launch_bounds__(256, 4)
calc_impute_mono(const float* __restrict__ dist,
                 const float* __restrict__ fitX,
                 const int*   __restrict__ mask,
                 float* __restrict__ out,
                 int nrows)
{
    const int gtid = blockIdx.x * blockDim.x + threadIdx.x;
    const int wrow = gtid >> 6;
    const int lane = threadIdx.x & 63;
    if (wrow >= nrows) return;

    const float4* __restrict__ r4 =
        reinterpret_cast<const float4*>(dist + (size_t)wrow * NDON);

    float4 d = r4[lane];
    float l0 = nanfix(d.x), l1 = nanfix(d.y), l2 = nanfix(d.z), l3 = nanfix(d.w);
    int   j0 = lane * 4, j1 = j0 + 1, j2 = j0 + 2, j3 = j0 + 3;
    CE(l0, j0, l1, j1); CE(l2, j2, l3, j3);
    CE(l0, j0, l2, j2); CE(l1, j1, l3, j3);
    CE(l1, j1, l2, j2);

    float vals[K]; int idxs[K];
#pragma unroll
    for (int r = 0; r < K; ++r) {
        float mv = l0; int mi = j0;
#pragma unroll
        for (int m = 32; m >= 1; m >>= 1) {
            const float ov = __shfl_xor(mv, m, 64);
            const int   oi = __shfl_xor(mi, m, 64);
            if (lexless(ov, oi, mv, mi)) { mv = ov; mi = oi; }
        }
        vals[r] = mv; idxs[r] = mi;
        if (l0 == mv && j0 == mi) {
            l0 = l1; j0 = j1; l1 = l2; j1 = j2; l2 = l3; j2 = j3;
            l3 = INFINITY; j3 = INT_MAX;
        }
    }
    float Tv = vals[K - 1];

#define PROCM(ve, ie)                                                  \
    {                                                                  \
        unsigned long long bb_ = __ballot((ve) <= Tv);                 \
        while (bb_) {                                                  \
            const int src_ = __builtin_ctzll(bb_); bb_ &= bb_ - 1;     \
            const float cv_ = __shfl((ve), src_, 64);                  \
            const int   ci_ = __shfl((ie), src_, 64);                  \
            insert16m(vals, idxs, cv_, ci_);                           \
        }                                                              \
    }

    const float4* p0 = r4 + 64 + lane;
    float4 c0 = p0[0], c1 = p0[64], c2 = p0[128], c3 = p0[192];
#pragma unroll 1
    for (int s = 0; s < 48; ++s) {
        float4 n0, n1, n2, n3;
        const bool more = (s + 1 < 48);
        if (more) {
            const float4* pn = r4 + 64 + (s + 1) * 256 + lane;
            n0 = pn[0]; n1 = pn[64]; n2 = pn[128]; n3 = pn[192];
        }
        const float m0 = fminf(fminf(c0.x, c0.y), fminf(c0.z, c0.w));
        const float m1 = fminf(fminf(c1.x, c1.y), fminf(c1.z, c1.w));
        const float m2 = fminf(fminf(c2.x, c2.y), fminf(c2.z, c2.w));
        const float m3 = fminf(fminf(c3.x, c3.y), fminf(c3.z, c3.w));
        if (__any(fminf(fminf(m0, m1), fminf(m2, m3)) <= Tv)) {
            const int e0 = (64 + s * 256 + lane) * 4;
            PROCM(c0.x, e0 + 0);   PROCM(c0.y, e0 + 1);
            PROCM(c0.z, e0 + 2);   PROCM(c0.w, e0 + 3);
            PROCM(c1.x, e0 + 256); PROCM(c1.y, e0 + 257);
            PROCM(c1.z, e0 + 258); PROCM(c1.w, e0 + 259);
            PROCM(c2.x, e0 + 512); PROCM(c2.y, e0 + 513);
            PROCM(c2.z, e0 + 514); PROCM(c2.w, e0 + 515);
            PROCM(c3.x, e0 + 768); PROCM(c3.y, e0 + 769);
            PROCM(c3.z, e0 + 770); PROCM(c3.w, e0 + 771);
            Tv = vals[K - 1];
        }
        c0 = n0; c1 = n1; c2 = n2; c3 = n3;
    }
#pragma unroll 1
    for (int t = 0; t < 3; ++t) {
        const int f4i = 12352 + t * 64 + lane;
        float4 e;
        if (f4i < NF4) { e = r4[f4i]; }
        else { e.x = e.y = e.z = e.w = INFINITY; }
        const int b0 = f4i * 4;
        PROCM(e.x, b0 + 0); PROCM(e.y, b0 + 1);
        PROCM(e.z, b0 + 2); PROCM(e.w, b0 + 3);
    }
#undef PROCM

    float s_w = 0.0f, s_wx = 0.0f;
#pragma unroll
    for (int r = 0; r < K; ++r) {
        const int mi = idxs[r];
        const float w = 1.0f - (float)mask[mi];
        s_w  += w;
        s_wx += w * fitX[mi];
    }
    if (lane == 0) {
        out[wrow] = s_wx / ((s_w == 0.0f) ? 1.0f : s_w);
    }
}

extern "C" void kernel_launch(void* const* d_in, const int* in_sizes, int n_in,
                              void* d_out, int out_size, void* d_ws, size_t ws_size,
                              hipStream_t stream) {
    const float* dist = (const float*)d_in[0];
    // d_in[1] is n_neighbors (==16, fixed; K hardcoded)
    const float* fitX = (const float*)d_in[2];
    const int*   mask = (const int*)d_in[3];
    float* out = (float*)d_out;
    const int nrows = out_size;                  // 8192

    const size_t needed = (size_t)NROWS * sizeof(int)
                        + (size_t)NROWS * CAP * sizeof(u64);
    if (ws_size >= needed) {
        int* cnt  = (int*)d_ws;
        u64* buck = (u64*)((char*)d_ws + NROWS * sizeof(int));
        k_zero<<<(NROWS + 255) / 256, 256, 0, stream>>>(cnt);
        k_scan<<<2048, 256, 0, stream>>>(
            reinterpret_cast<const float4*>(dist), buck, cnt);
        k_merge<<<nrows, 64, 0, stream>>>(buck, cnt, dist, fitX, mask, out, nrows);
    } else {
        const int threads = 256;
        const int blocks = (nrows * 64 + threads - 1) / threads;
        calc_impute_mono<<<blocks, threads, 0, stream>>>(dist, fitX, mask, out, nrows);
    }
}